// Round 1
// baseline (9356.018 us; speedup 1.0000x reference)
//
#include <hip/hip_runtime.h>
#include <math.h>

// ---------------- problem constants ----------------
constexpr int Bc  = 256;   // batch
constexpr int Tc  = 64;    // time
constexpr int Ac  = 64;    // action dim
constexpr int Ec  = 1024;  // obs embed
constexpr int HIDc = 1024;
constexpr int DETc = 2048;
constexpr int STOc = 256;

typedef __attribute__((ext_vector_type(8))) short  s8v;
typedef __attribute__((ext_vector_type(8))) __bf16 bf8v;
typedef __attribute__((ext_vector_type(4))) float  f4v;

__device__ inline unsigned short f2bf(float f) {
  union { float f; unsigned u; } v; v.f = f;
  return (unsigned short)((v.u + 0x7FFF + ((v.u >> 16) & 1)) >> 16); // RNE
}
__device__ inline float sigm(float x) { return 1.0f / (1.0f + expf(-x)); }
__device__ inline float softplusf(float x) {
  return fmaxf(x, 0.0f) + log1pf(expf(-fabsf(x)));
}
__device__ inline f4v mfma16(bf8v a, bf8v b, f4v c) {
  return __builtin_amdgcn_mfma_f32_16x16x32_bf16(a, b, c, 0, 0, 0);
}

// ---------------- precompute kernels ----------------
__global__ void k_cvt(const float* __restrict__ in, unsigned short* __restrict__ out, int n) {
  int i = blockIdx.x * 256 + threadIdx.x;
  if (i < n) out[i] = f2bf(in[i]);
}
// out[n*opitch + k] = bf16(in[k*ipitch + n])
__global__ void k_tr(const float* __restrict__ in, int ipitch,
                     unsigned short* __restrict__ out, int opitch, int N, int K) {
  int k = blockIdx.x * 16 + (threadIdx.x & 15);
  int n = blockIdx.y * 16 + (threadIdx.x >> 4);
  if (k < K && n < N) out[n * opitch + k] = f2bf(in[k * ipitch + n]);
}
// a_shift[t][b][j] = (t==0) ? 0 : bf16(actions[b][t-1][j])
__global__ void k_ashift(const float* __restrict__ actions, unsigned short* __restrict__ out) {
  int i = blockIdx.x * 256 + threadIdx.x;
  if (i >= Tc * Bc * Ac) return;
  int j = i & 63, b = (i >> 6) & 255, t = i >> 14;
  out[i] = (t == 0) ? (unsigned short)0 : f2bf(actions[(b * Tc + (t - 1)) * Ac + j]);
}
__global__ void k_zero16(unsigned short* p, int n) {
  int i = blockIdx.x * 256 + threadIdx.x;
  if (i < n) p[i] = 0;
}

// ---------------- S1: rnn_in = relu([z|a_prev] @ W_rnn + b) ----------------
// A: [256 x 320] (cols 0:256 Zb, 256:320 a_t), Bt: Wrnn_t [1024 x 320], C-> X[:,0:1024] bf16
__global__ __launch_bounds__(256) void k_s1(
    const unsigned short* __restrict__ Zb, const unsigned short* __restrict__ a_t,
    const unsigned short* __restrict__ Wrnn_t, const float* __restrict__ b_rnn,
    unsigned short* __restrict__ X) {
  __shared__ __align__(16) short lds[(64 + 64) * 72];
  const int tid = threadIdx.x, lane = tid & 63, wv = tid >> 6;
  const int m0 = blockIdx.y * 64, n0 = blockIdx.x * 64;
  f4v acc[4] = {};
  short* A_l = lds;
  short* B_l = lds + 64 * 72;
  for (int k0 = 0; k0 < 320; k0 += 64) {
    __syncthreads();
    for (int it = 0; it < 2; ++it) {
      int idx = tid + it * 256, row = idx >> 3, cs = (idx & 7) * 8;
      int k = k0 + cs;
      const unsigned short* src = (k < 256) ? (Zb + (m0 + row) * 256 + k)
                                            : (a_t + (m0 + row) * 64 + (k - 256));
      *(s8v*)&A_l[row * 72 + cs] = *(const s8v*)src;
    }
    for (int it = 0; it < 2; ++it) {
      int idx = tid + it * 256, row = idx >> 3, cs = (idx & 7) * 8;
      *(s8v*)&B_l[row * 72 + cs] = *(const s8v*)(Wrnn_t + (n0 + row) * 320 + k0 + cs);
    }
    __syncthreads();
    const int qa = (lane >> 4) * 8;
#pragma unroll
    for (int kk = 0; kk < 64; kk += 32) {
      bf8v af = *(const bf8v*)&A_l[(wv * 16 + (lane & 15)) * 72 + kk + qa];
#pragma unroll
      for (int ni = 0; ni < 4; ni++) {
        bf8v bf = *(const bf8v*)&B_l[(ni * 16 + (lane & 15)) * 72 + kk + qa];
        acc[ni] = mfma16(af, bf, acc[ni]);
      }
    }
  }
  const int mrow = m0 + wv * 16 + (lane >> 4) * 4;
#pragma unroll
  for (int ni = 0; ni < 4; ni++) {
    int gn = n0 + ni * 16 + (lane & 15);
    float bias = b_rnn[gn];
#pragma unroll
    for (int r = 0; r < 4; r++) {
      float v = acc[ni][r] + bias;
      X[(mrow + r) * 3072 + gn] = f2bf(v > 0.0f ? v : 0.0f);
    }
  }
}

// ---------------- S2: fused GRU gates + h ----------------
// X: [256 x 3072] = [rnn_in | h_prev] bf16. Gates r,u: K=0..3072; new_i: K=0..1024 (Wih);
// new_h: K=1024..3072 (Whh). Epilogue: h -> d_out(f32) and X[:,1024:3072](bf16).
__global__ __launch_bounds__(256) void k_s2(
    const unsigned short* __restrict__ X,
    const unsigned short* __restrict__ Wih, const unsigned short* __restrict__ Whh,
    const float* __restrict__ bih, const float* __restrict__ bhh,
    const float* __restrict__ h_prev, int t0flag,
    float* __restrict__ h_out, unsigned short* __restrict__ Xh) {
  __shared__ __align__(16) short lds[(64 + 3 * 32) * 72];
  const int tid = threadIdx.x, lane = tid & 63, wv = tid >> 6;
  const int m0 = blockIdx.y * 64, d0 = blockIdx.x * 32;
  f4v acc[4][2] = {};  // r, u, new_i, new_h
  short* A_l = lds;
  short* B_l = lds + 64 * 72;
  for (int k0 = 0; k0 < 3072; k0 += 64) {
    const bool ih = (k0 < 1024);
    __syncthreads();
    for (int it = 0; it < 2; ++it) {
      int idx = tid + it * 256, row = idx >> 3, cs = (idx & 7) * 8;
      *(s8v*)&A_l[row * 72 + cs] = *(const s8v*)(X + (m0 + row) * 3072 + k0 + cs);
    }
    {
      int row = tid >> 3, cs = (tid & 7) * 8;
      const unsigned short* Wsrc = ih ? Wih : Whh;
      int pitch = ih ? 1024 : 2048;
      int kk0 = ih ? k0 : (k0 - 1024);
#pragma unroll
      for (int g = 0; g < 3; ++g) {
        int grow = g * 2048 + d0 + row;
        *(s8v*)&B_l[(g * 32 + row) * 72 + cs] = *(const s8v*)(Wsrc + grow * pitch + kk0 + cs);
      }
    }
    __syncthreads();
    const int qa = (lane >> 4) * 8;
#pragma unroll
    for (int kk = 0; kk < 64; kk += 32) {
      bf8v af = *(const bf8v*)&A_l[(wv * 16 + (lane & 15)) * 72 + kk + qa];
#pragma unroll
      for (int ni = 0; ni < 2; ni++) {
        bf8v b0 = *(const bf8v*)&B_l[(0 * 32 + ni * 16 + (lane & 15)) * 72 + kk + qa];
        bf8v b1 = *(const bf8v*)&B_l[(1 * 32 + ni * 16 + (lane & 15)) * 72 + kk + qa];
        bf8v b2 = *(const bf8v*)&B_l[(2 * 32 + ni * 16 + (lane & 15)) * 72 + kk + qa];
        acc[0][ni] = mfma16(af, b0, acc[0][ni]);
        acc[1][ni] = mfma16(af, b1, acc[1][ni]);
        if (ih) acc[2][ni] = mfma16(af, b2, acc[2][ni]);
        else    acc[3][ni] = mfma16(af, b2, acc[3][ni]);
      }
    }
  }
  const int mrow = m0 + wv * 16 + (lane >> 4) * 4;
#pragma unroll
  for (int ni = 0; ni < 2; ni++) {
    int d = d0 + ni * 16 + (lane & 15);
    float br = bih[d] + bhh[d];
    float bu = bih[2048 + d] + bhh[2048 + d];
    float bi = bih[4096 + d];
    float bh = bhh[4096 + d];
#pragma unroll
    for (int r = 0; r < 4; r++) {
      int m = mrow + r;
      float rg = sigm(acc[0][ni][r] + br);
      float ug = sigm(acc[1][ni][r] + bu);
      float ng = tanhf(acc[2][ni][r] + bi + rg * (acc[3][ni][r] + bh));
      float hp = t0flag ? 0.0f : h_prev[m * (Tc * DETc) + d];
      float h = (1.0f - ug) * ng + ug * hp;
      h_out[m * (Tc * DETc) + d] = h;
      Xh[m * 3072 + d] = f2bf(h);
    }
  }
}

// ---------------- S4: pf|rf = relu(h @ [Wpost_h|Wprior] (+ obs @ Wobs) + b) ----------------
__global__ __launch_bounds__(256) void k_s4(
    const unsigned short* __restrict__ Xh,   // X+1024, pitch 3072
    const float* __restrict__ obs_t,         // obs_embed + t*E, row pitch T*E
    const unsigned short* __restrict__ Wpr_t, const unsigned short* __restrict__ Wobs_t,
    const float* __restrict__ b_post_in, const float* __restrict__ b_prior_in,
    unsigned short* __restrict__ X3) {
  __shared__ __align__(16) short lds[(64 + 32) * 72];
  const int tid = threadIdx.x, lane = tid & 63, wv = tid >> 6;
  const int m0 = blockIdx.y * 64, n0 = blockIdx.x * 32;
  const bool is_pf = (n0 < 1024);
  const int Ktot = is_pf ? 3072 : 2048;
  f4v acc[2] = {};
  short* A_l = lds;
  short* B_l = lds + 64 * 72;
  for (int k0 = 0; k0 < Ktot; k0 += 64) {
    __syncthreads();
    if (k0 < 2048) {
      for (int it = 0; it < 2; ++it) {
        int idx = tid + it * 256, row = idx >> 3, cs = (idx & 7) * 8;
        *(s8v*)&A_l[row * 72 + cs] = *(const s8v*)(Xh + (m0 + row) * 3072 + k0 + cs);
      }
      int row = tid >> 3, cs = (tid & 7) * 8;
      *(s8v*)&B_l[row * 72 + cs] = *(const s8v*)(Wpr_t + (n0 + row) * 2048 + k0 + cs);
    } else {
      int ke = k0 - 2048;
      for (int it = 0; it < 2; ++it) {
        int idx = tid + it * 256, row = idx >> 3, cs = (idx & 7) * 8;
        const float* s = obs_t + (size_t)(m0 + row) * (Tc * Ec) + ke + cs;
        s8v v;
#pragma unroll
        for (int j = 0; j < 8; j++) v[j] = (short)f2bf(s[j]);
        *(s8v*)&A_l[row * 72 + cs] = v;
      }
      int row = tid >> 3, cs = (tid & 7) * 8;
      *(s8v*)&B_l[row * 72 + cs] = *(const s8v*)(Wobs_t + (n0 + row) * 1024 + ke + cs);
    }
    __syncthreads();
    const int qa = (lane >> 4) * 8;
#pragma unroll
    for (int kk = 0; kk < 64; kk += 32) {
      bf8v af = *(const bf8v*)&A_l[(wv * 16 + (lane & 15)) * 72 + kk + qa];
#pragma unroll
      for (int ni = 0; ni < 2; ni++) {
        bf8v bf = *(const bf8v*)&B_l[(ni * 16 + (lane & 15)) * 72 + kk + qa];
        acc[ni] = mfma16(af, bf, acc[ni]);
      }
    }
  }
  const int mrow = m0 + wv * 16 + (lane >> 4) * 4;
#pragma unroll
  for (int ni = 0; ni < 2; ni++) {
    int n = n0 + ni * 16 + (lane & 15);
    float bias = is_pf ? b_post_in[n] : b_prior_in[n - 1024];
#pragma unroll
    for (int r = 0; r < 4; r++) {
      float v = acc[ni][r] + bias;
      X3[(mrow + r) * 2048 + n] = f2bf(v > 0.0f ? v : 0.0f);
    }
  }
}

// ---------------- S5: pm/pls/qm/qls + softplus + rsample ----------------
__global__ __launch_bounds__(256) void k_s5(
    const unsigned short* __restrict__ X3, const unsigned short* __restrict__ Wms_t,
    const float* __restrict__ b_post_ms, const float* __restrict__ b_prior_ms,
    const float* __restrict__ noise_t,
    float* __restrict__ out_z, float* __restrict__ out_pm, float* __restrict__ out_ps,
    float* __restrict__ out_qm, float* __restrict__ out_qs,
    unsigned short* __restrict__ Zb) {
  __shared__ __align__(16) short lds[(64 + 2 * 32) * 72];
  const int tid = threadIdx.x, lane = tid & 63, wv = tid >> 6;
  const int m0 = blockIdx.y * 64, j0 = blockIdx.x * 32;
  f4v acc[4][2] = {};  // pm, pls, qm, qls
  short* A_l = lds;
  short* B_l = lds + 64 * 72;
  for (int k0 = 0; k0 < 2048; k0 += 64) {
    const bool post = (k0 < 1024);
    __syncthreads();
    for (int it = 0; it < 2; ++it) {
      int idx = tid + it * 256, row = idx >> 3, cs = (idx & 7) * 8;
      *(s8v*)&A_l[row * 72 + cs] = *(const s8v*)(X3 + (m0 + row) * 2048 + k0 + cs);
    }
    {
      int row = tid >> 3, cs = (tid & 7) * 8;
      int base = (post ? 0 : 512) + j0 + row;
      int kk0 = k0 & 1023;
      *(s8v*)&B_l[row * 72 + cs]        = *(const s8v*)(Wms_t + base * 1024 + kk0 + cs);
      *(s8v*)&B_l[(32 + row) * 72 + cs] = *(const s8v*)(Wms_t + (base + 256) * 1024 + kk0 + cs);
    }
    __syncthreads();
    const int qa = (lane >> 4) * 8;
    const int a0 = post ? 0 : 2, a1 = post ? 1 : 3;
#pragma unroll
    for (int kk = 0; kk < 64; kk += 32) {
      bf8v af = *(const bf8v*)&A_l[(wv * 16 + (lane & 15)) * 72 + kk + qa];
#pragma unroll
      for (int ni = 0; ni < 2; ni++) {
        bf8v b0 = *(const bf8v*)&B_l[(ni * 16 + (lane & 15)) * 72 + kk + qa];
        bf8v b1 = *(const bf8v*)&B_l[(32 + ni * 16 + (lane & 15)) * 72 + kk + qa];
        acc[a0][ni] = mfma16(af, b0, acc[a0][ni]);
        acc[a1][ni] = mfma16(af, b1, acc[a1][ni]);
      }
    }
  }
  const int mrow = m0 + wv * 16 + (lane >> 4) * 4;
#pragma unroll
  for (int ni = 0; ni < 2; ni++) {
    int j = j0 + ni * 16 + (lane & 15);
    float bpm = b_post_ms[j], bpl = b_post_ms[256 + j];
    float bqm = b_prior_ms[j], bql = b_prior_ms[256 + j];
#pragma unroll
    for (int r = 0; r < 4; r++) {
      int m = mrow + r;
      float pm = acc[0][ni][r] + bpm;
      float ps = softplusf(acc[1][ni][r] + bpl) + 0.1f;
      float qm = acc[2][ni][r] + bqm;
      float qs = softplusf(acc[3][ni][r] + bql) + 0.1f;
      float z = pm + ps * noise_t[m * (Tc * STOc) + j];
      int o = m * (Tc * STOc) + j;
      out_pm[o] = pm; out_ps[o] = ps; out_qm[o] = qm; out_qs[o] = qs; out_z[o] = z;
      Zb[m * 256 + j] = f2bf(z);
    }
  }
}

// ---------------- host ----------------
extern "C" void kernel_launch(void* const* d_in, const int* in_sizes, int n_in,
                              void* d_out, int out_size, void* d_ws, size_t ws_size,
                              hipStream_t stream) {
  const float* obs      = (const float*)d_in[0];
  const float* actions  = (const float*)d_in[1];
  const float* noise    = (const float*)d_in[4];
  const float* W_rnn    = (const float*)d_in[5];
  const float* b_rnn    = (const float*)d_in[6];
  const float* Wih      = (const float*)d_in[7];
  const float* Whh      = (const float*)d_in[8];
  const float* bih      = (const float*)d_in[9];
  const float* bhh      = (const float*)d_in[10];
  const float* Wpost_in = (const float*)d_in[11];
  const float* b_post_in= (const float*)d_in[12];
  const float* Wpost_ms = (const float*)d_in[13];
  const float* b_post_ms= (const float*)d_in[14];
  const float* Wprior_in= (const float*)d_in[15];
  const float* b_prior_in=(const float*)d_in[16];
  const float* Wprior_ms= (const float*)d_in[17];
  const float* b_prior_ms=(const float*)d_in[18];

  float* out    = (float*)d_out;
  float* out_h  = out;
  float* out_z  = out_h  + (size_t)Bc * Tc * DETc;
  float* out_pm = out_z  + (size_t)Bc * Tc * STOc;
  float* out_ps = out_pm + (size_t)Bc * Tc * STOc;
  float* out_qm = out_ps + (size_t)Bc * Tc * STOc;
  float* out_qs = out_qm + (size_t)Bc * Tc * STOc;

  char* w = (char*)d_ws;
  auto alloc = [&](size_t bytes) -> char* {
    char* p = w; w += (bytes + 255) & ~(size_t)255; return p;
  };
  unsigned short* Wih_b   = (unsigned short*)alloc((size_t)6144 * 1024 * 2);
  unsigned short* Whh_b   = (unsigned short*)alloc((size_t)6144 * 2048 * 2);
  unsigned short* Wrnn_t  = (unsigned short*)alloc((size_t)1024 * 320 * 2);
  unsigned short* Wpr_t   = (unsigned short*)alloc((size_t)2048 * 2048 * 2);
  unsigned short* Wobs_t  = (unsigned short*)alloc((size_t)1024 * 1024 * 2);
  unsigned short* Wms_t   = (unsigned short*)alloc((size_t)1024 * 1024 * 2);
  unsigned short* a_shift = (unsigned short*)alloc((size_t)Tc * Bc * Ac * 2);
  unsigned short* Xbuf    = (unsigned short*)alloc((size_t)256 * 3072 * 2);
  unsigned short* Zb      = (unsigned short*)alloc((size_t)256 * 256 * 2);
  unsigned short* X3      = (unsigned short*)alloc((size_t)256 * 2048 * 2);

  // weight conversion / layout builds (re-done every call: ws is re-poisoned)
  k_cvt<<<(6144 * 1024 + 255) / 256, 256, 0, stream>>>(Wih, Wih_b, 6144 * 1024);
  k_cvt<<<(6144 * 2048 + 255) / 256, 256, 0, stream>>>(Whh, Whh_b, 6144 * 2048);
  k_tr<<<dim3(20, 64),  256, 0, stream>>>(W_rnn, 1024, Wrnn_t, 320, 1024, 320);
  k_tr<<<dim3(128, 64), 256, 0, stream>>>(Wpost_in, 1024, Wpr_t, 2048, 1024, 2048);
  k_tr<<<dim3(128, 64), 256, 0, stream>>>(Wprior_in, 1024, Wpr_t + (size_t)1024 * 2048, 2048, 1024, 2048);
  k_tr<<<dim3(64, 64),  256, 0, stream>>>(Wpost_in + (size_t)2048 * 1024, 1024, Wobs_t, 1024, 1024, 1024);
  k_tr<<<dim3(64, 32),  256, 0, stream>>>(Wpost_ms, 512, Wms_t, 1024, 512, 1024);
  k_tr<<<dim3(64, 32),  256, 0, stream>>>(Wprior_ms, 512, Wms_t + (size_t)512 * 1024, 1024, 512, 1024);
  k_ashift<<<(Tc * Bc * Ac + 255) / 256, 256, 0, stream>>>(actions, a_shift);
  k_zero16<<<(256 * 3072 + 255) / 256, 256, 0, stream>>>(Xbuf, 256 * 3072);
  k_zero16<<<(256 * 256 + 255) / 256, 256, 0, stream>>>(Zb, 256 * 256);

  for (int t = 0; t < Tc; ++t) {
    k_s1<<<dim3(16, 4), 256, 0, stream>>>(Zb, a_shift + (size_t)t * Bc * Ac, Wrnn_t, b_rnn, Xbuf);
    k_s2<<<dim3(64, 4), 256, 0, stream>>>(Xbuf, Wih_b, Whh_b, bih, bhh,
        (t == 0) ? out_h : (out_h + (size_t)(t - 1) * DETc), (t == 0) ? 1 : 0,
        out_h + (size_t)t * DETc, Xbuf + 1024);
    k_s4<<<dim3(64, 4), 256, 0, stream>>>(Xbuf + 1024, obs + (size_t)t * Ec,
        Wpr_t, Wobs_t, b_post_in, b_prior_in, X3);
    k_s5<<<dim3(8, 4), 256, 0, stream>>>(X3, Wms_t, b_post_ms, b_prior_ms,
        noise + (size_t)t * STOc,
        out_z + (size_t)t * STOc, out_pm + (size_t)t * STOc, out_ps + (size_t)t * STOc,
        out_qm + (size_t)t * STOc, out_qs + (size_t)t * STOc, Zb);
  }
}